// Round 11
// baseline (61.846 us; speedup 1.0000x reference)
//
#include <hip/hip_runtime.h>

// GCLSTM (K=1 Cheb, H0=C0=0) fused kernel for MI355X — v11.
// Math: i=sig(x@Wi+bi'), t=tanh(x@Wc+bc'), C=i*t, o=sig(x@Wo+bo'+wco*C),
//       out = (o*tanh(C)) @ fcW + fcb.  edge_index/batch/Wg_*/W_f unused.
// v11 = v9 dataflow (zero-LDS zero-shuffle permuted-h, prescaled exp2-direct
//     gates, cvt_pk) at m=1: 16 rows/wave -> 12500 waves (48.8/CU supply),
//     saturating the 32-wave/CU residency cap with ~2x shorter chains.
//     ~Half the register state of v9 (expect ~50 VGPR -> 8 waves/SIMD by
//     actual usage). 4-wave 256-thread WGs (3125), no barriers, no rot.

typedef __attribute__((ext_vector_type(8))) short short8;
typedef __attribute__((ext_vector_type(4))) float f32x4;

#define N_ROWS 200000
#define IN_DIM 64
#define HID 128
#define OUT_DIM 64

#define LOG2E 1.44269504f
#define TWOLOG2E 2.88539008f

// ws layout (bytes)
#define WFRAG_ELEMS (24 * 2 * 64 * 8)   // 24576 bf16 = 49152 B
#define FCFRAG_OFF  49152               // WFRAG_ELEMS*2
#define FCFRAG_ELEMS (4 * 4 * 64 * 8)   // 8192 bf16 = 16384 B
#define BIAS_OFF    65536               // floats: si[128],sc[128],so[128],swc[128] (h-permuted, prescaled), fcb[64]

__device__ __forceinline__ short f2bf(float f) {
  unsigned u = __float_as_uint(f);
  u += 0x7FFFu + ((u >> 16) & 1u);   // RNE (repack only)
  return (short)(u >> 16);
}
__device__ __forceinline__ unsigned cvt_pk_bf16(float lo, float hi) {
  unsigned r;
  asm("v_cvt_pk_bf16_f32 %0, %1, %2" : "=v"(r) : "v"(lo), "v"(hi));
  return r;
}
__device__ __forceinline__ float fexp2(float z) { return __builtin_amdgcn_exp2f(z); }
__device__ __forceinline__ float frcp(float z)  { return __builtin_amdgcn_rcpf(z); }
// permuted global hid for GEMM1 tile g (0..7), D-row d (0..15)
__device__ __forceinline__ int hperm(int g, int d) {
  return 32 * (g >> 1) + 2 * (g & 1) + 8 * (d >> 2) + 4 * ((d >> 1) & 1) + (d & 1);
}

// ---- repack: weights -> bf16 MFMA A-fragments (PRESCALED), biases fp32 ----
__global__ void repack_kernel(const float* __restrict__ W_i, const float* __restrict__ W_c,
                              const float* __restrict__ W_o, const float* __restrict__ fc_W,
                              const float* __restrict__ bg_i, const float* __restrict__ bg_c,
                              const float* __restrict__ bg_o,
                              const float* __restrict__ b_i, const float* __restrict__ b_c,
                              const float* __restrict__ b_o, const float* __restrict__ wc_o,
                              const float* __restrict__ fc_b,
                              short* __restrict__ wfrag, short* __restrict__ fcfrag,
                              float* __restrict__ bias) {
  int tid = blockIdx.x * blockDim.x + threadIdx.x;
  const int total1 = WFRAG_ELEMS;
  const int total2 = FCFRAG_ELEMS;
  for (int e = tid; e < total1 + total2 + HID + OUT_DIM; e += gridDim.x * blockDim.x) {
    if (e < total1) {
      // A-frag of GEMM1: D-row cidx of tile g, k=32s+8q+j, PERMUTED h, PRESCALED
      int j = e & 7, lane = (e >> 3) & 63, s = (e >> 9) & 1, t = e >> 10;
      int q = lane >> 4, cidx = lane & 15;
      int gate = t >> 3;                       // 0:W_i 1:W_c 2:W_o
      int g = t & 7;
      int h = hperm(g, cidx);
      int feat = 32 * s + 8 * q + j;
      const float* W = (gate == 0) ? W_i : ((gate == 1) ? W_c : W_o);
      float scale = (gate == 1) ? TWOLOG2E : -LOG2E;
      wfrag[e] = f2bf(W[feat * HID + h] * scale);
    } else if (e < total1 + total2) {
      // A-frag of GEMM2: A = fc_W^T (64x128), STANDARD hid = 32s+8q+j
      int e2 = e - total1;
      int j = e2 & 7, lane = (e2 >> 3) & 63, s = (e2 >> 9) & 3, t = e2 >> 11;
      int q = lane >> 4, cidx = lane & 15;
      int od = 16 * t + cidx;
      int hid = 32 * s + 8 * q + j;
      fcfrag[e2] = f2bf(fc_W[hid * OUT_DIM + od]);
    } else if (e < total1 + total2 + HID) {
      int p = e - total1 - total2;             // permuted storage index g*16+d
      int h = hperm(p >> 4, p & 15);
      bias[p]           = -LOG2E  * (bg_i[h] + b_i[h]);
      bias[HID + p]     = TWOLOG2E * (bg_c[h] + b_c[h]);
      bias[2 * HID + p] = -LOG2E  * (bg_o[h] + b_o[h]);
      bias[3 * HID + p] = -LOG2E  * wc_o[h];
    } else {
      int h2 = e - total1 - total2 - HID;
      bias[4 * HID + h2] = fc_b[h2];
    }
  }
}

// ---- fused main kernel: 16 rows/wave, 4-wave WGs, no LDS, no barriers ----
__global__ __launch_bounds__(256, 4) void gclstm_fused(
    const float* __restrict__ x, const short* __restrict__ wfrag,
    const short* __restrict__ fcfrag, const float* __restrict__ bias,
    float* __restrict__ out) {
  const int tid = threadIdx.x;
  const int lane = tid & 63;
  const int wid = (blockIdx.x * 256 + tid) >> 6;   // 0..12499
  const size_t row0 = (size_t)wid * 16;            // 12500*16 = 200000 exact
  const int q = lane >> 4, c = lane & 15;
  const short* wf = wfrag + lane * 8;
  const short* ff = fcfrag + lane * 8;

  union U { unsigned u[4]; short8 s8; };

  // x B-fragment: B = x^T; lane supplies col (row row0+c), k=32sk+8q+j
  short8 bx[2];
  {
    const float* xr = x + (row0 + c) * IN_DIM + 8 * q;
#pragma unroll
    for (int sk = 0; sk < 2; ++sk) {
      f32x4 f0 = *(const f32x4*)(xr + 32 * sk);
      f32x4 f1 = *(const f32x4*)(xr + 32 * sk + 4);
      U v;
      v.u[0] = cvt_pk_bf16(f0[0], f0[1]);
      v.u[1] = cvt_pk_bf16(f0[2], f0[3]);
      v.u[2] = cvt_pk_bf16(f1[0], f1[1]);
      v.u[3] = cvt_pk_bf16(f1[2], f1[3]);
      bx[sk] = v.s8;
    }
  }

  const float* Si  = bias;               // prescaled, permuted (index g*16+d)
  const float* Sc  = bias + HID;
  const float* So  = bias + 2 * HID;
  const float* Swc = bias + 3 * HID;
  const float* Fcb = bias + 4 * HID;     // standard od order

  // ---- Phase 1: 8 GEMM1 h-tiles + gates; H banked in 16 u32 regs ----
  unsigned hbuf[8][2];                   // [g][word]
#pragma unroll
  for (int g = 0; g < 8; ++g) {
    const int p0 = g * 16 + 4 * q;
    f32x4 acc0 = *(const f32x4*)(Si + p0);
    f32x4 acc1 = *(const f32x4*)(Sc + p0);
    f32x4 acc2 = *(const f32x4*)(So + p0);
    f32x4 vwc  = *(const f32x4*)(Swc + p0);
#pragma unroll
    for (int sk = 0; sk < 2; ++sk) {
      short8 ai = *(const short8*)(wf + ((g     ) * 2 + sk) * 512);
      short8 ac = *(const short8*)(wf + ((g +  8) * 2 + sk) * 512);
      short8 ao = *(const short8*)(wf + ((g + 16) * 2 + sk) * 512);
      acc0 = __builtin_amdgcn_mfma_f32_16x16x32_bf16(ai, bx[sk], acc0, 0, 0, 0);
      acc1 = __builtin_amdgcn_mfma_f32_16x16x32_bf16(ac, bx[sk], acc1, 0, 0, 0);
      acc2 = __builtin_amdgcn_mfma_f32_16x16x32_bf16(ao, bx[sk], acc2, 0, 0, 0);
    }
    // gates (prescaled): ei=e^-zi, ec=e^2zc; C=(ec-1)*rcp((1+ei)(1+ec));
    // eo=e^-(zo+wc*C) via prescale; e2=e^2C; H=(e2-1)*rcp((1+eo)(1+e2)).
    f32x4 ei, ec;
#pragma unroll
    for (int r = 0; r < 4; ++r) { ei[r] = fexp2(acc0[r]); ec[r] = fexp2(acc1[r]); }
    f32x4 den1 = (ei + 1.0f) * (ec + 1.0f);
    f32x4 rd1;
#pragma unroll
    for (int r = 0; r < 4; ++r) rd1[r] = frcp(den1[r]);
    f32x4 C = (ec - 1.0f) * rd1;
    f32x4 s2 = acc2 + vwc * C;
    f32x4 t2 = C * TWOLOG2E;
    f32x4 eo, e2;
#pragma unroll
    for (int r = 0; r < 4; ++r) { eo[r] = fexp2(s2[r]); e2[r] = fexp2(t2[r]); }
    f32x4 den2 = (eo + 1.0f) * (e2 + 1.0f);
    f32x4 rd2;
#pragma unroll
    for (int r = 0; r < 4; ++r) rd2[r] = frcp(den2[r]);
    f32x4 H = (e2 - 1.0f) * rd2;
    hbuf[g][0] = cvt_pk_bf16(H[0], H[1]);
    hbuf[g][1] = cvt_pk_bf16(H[2], H[3]);
  }

  // ---- Phase 2: GEMM2 dense block; oacc init = fc bias (folded) ----
  f32x4 oacc[4];
#pragma unroll
  for (int t = 0; t < 4; ++t) oacc[t] = *(const f32x4*)(Fcb + 16 * t + 4 * q);
#pragma unroll
  for (int s = 0; s < 4; ++s) {
    U bu;
    bu.u[0] = hbuf[2 * s][0];
    bu.u[1] = hbuf[2 * s + 1][0];
    bu.u[2] = hbuf[2 * s][1];
    bu.u[3] = hbuf[2 * s + 1][1];
#pragma unroll
    for (int t = 0; t < 4; ++t) {
      short8 af = *(const short8*)(ff + (t * 4 + s) * 512);
      oacc[t] = __builtin_amdgcn_mfma_f32_16x16x32_bf16(af, bu.s8, oacc[t], 0, 0, 0);
    }
  }

  // ---- epilogue: coalesced float4 stores ----
#pragma unroll
  for (int t = 0; t < 4; ++t) {
    *(f32x4*)(out + (row0 + c) * OUT_DIM + 16 * t + 4 * q) = oacc[t];
  }
}

extern "C" void kernel_launch(void* const* d_in, const int* in_sizes, int n_in,
                              void* d_out, int out_size, void* d_ws, size_t ws_size,
                              hipStream_t stream) {
  (void)in_sizes; (void)n_in; (void)out_size; (void)ws_size;
  const float* x    = (const float*)d_in[0];
  const float* W_i  = (const float*)d_in[3];
  const float* W_c  = (const float*)d_in[5];
  const float* W_o  = (const float*)d_in[6];
  const float* bg_i = (const float*)d_in[11];
  const float* bg_c = (const float*)d_in[13];
  const float* bg_o = (const float*)d_in[14];
  const float* wc_o = (const float*)d_in[17];
  const float* b_i  = (const float*)d_in[18];
  const float* b_c  = (const float*)d_in[20];
  const float* b_o  = (const float*)d_in[21];
  const float* fc_W = (const float*)d_in[22];
  const float* fc_b = (const float*)d_in[23];

  short* wfrag  = (short*)d_ws;
  short* fcfrag = (short*)((char*)d_ws + FCFRAG_OFF);
  float* bias   = (float*)((char*)d_ws + BIAS_OFF);

  repack_kernel<<<dim3(64), dim3(256), 0, stream>>>(
      W_i, W_c, W_o, fc_W, bg_i, bg_c, bg_o, b_i, b_c, b_o, wc_o, fc_b,
      wfrag, fcfrag, bias);

  const int nwaves = N_ROWS / 16;           // 12500 waves, 16 rows each
  const int nwg = nwaves / 4;               // 3125 (256-thread WGs, 4 waves)
  gclstm_fused<<<dim3(nwg), dim3(256), 0, stream>>>(
      x, wfrag, fcfrag, bias, (float*)d_out);
}

// Round 14
// 58.012 us; speedup vs baseline: 1.0661x; 1.0661x over previous
//
#include <hip/hip_runtime.h>

// GCLSTM (K=1 Cheb, H0=C0=0) fused kernel for MI355X — v14.
// Math: i=sig(x@Wi+bi'), t=tanh(x@Wc+bc'), C=i*t, o=sig(x@Wo+bo'+wco*C),
//       out = (o*tanh(C)) @ fcW + fcb.  edge_index/batch/Wg_*/W_f unused.
// v14 = v9 EXACTLY + non-temporal x loads / out stores (nt flag).
//     Theory: 101 MB of zero-reuse stream traffic thrashes the 4MB/XCD L2,
//     evicting the 64KB weight set -> every weight load is L3-latency
//     (~500cy) and the per-wave serial chain is ~60 such events (~20us
//     residency). nt keeps streams out of L2; weights become L2-resident.

typedef __attribute__((ext_vector_type(8))) short short8;
typedef __attribute__((ext_vector_type(4))) float f32x4;

#define N_ROWS 200000
#define IN_DIM 64
#define HID 128
#define OUT_DIM 64

#define LOG2E 1.44269504f
#define TWOLOG2E 2.88539008f

// ws layout (bytes)
#define WFRAG_ELEMS (24 * 2 * 64 * 8)   // 24576 bf16 = 49152 B
#define FCFRAG_OFF  49152               // WFRAG_ELEMS*2
#define FCFRAG_ELEMS (4 * 4 * 64 * 8)   // 8192 bf16 = 16384 B
#define BIAS_OFF    65536               // floats: si[128],sc[128],so[128],swc[128] (h-permuted, prescaled), fcb[64]

__device__ __forceinline__ short f2bf(float f) {
  unsigned u = __float_as_uint(f);
  u += 0x7FFFu + ((u >> 16) & 1u);   // RNE (repack only)
  return (short)(u >> 16);
}
__device__ __forceinline__ unsigned cvt_pk_bf16(float lo, float hi) {
  unsigned r;
  asm("v_cvt_pk_bf16_f32 %0, %1, %2" : "=v"(r) : "v"(lo), "v"(hi));
  return r;
}
__device__ __forceinline__ float fexp2(float z) { return __builtin_amdgcn_exp2f(z); }
__device__ __forceinline__ float frcp(float z)  { return __builtin_amdgcn_rcpf(z); }
// permuted global hid for GEMM1 tile g (0..7), D-row d (0..15)
__device__ __forceinline__ int hperm(int g, int d) {
  return 32 * (g >> 1) + 2 * (g & 1) + 8 * (d >> 2) + 4 * ((d >> 1) & 1) + (d & 1);
}

// ---- repack: weights -> bf16 MFMA A-fragments (PRESCALED), biases fp32 ----
__global__ void repack_kernel(const float* __restrict__ W_i, const float* __restrict__ W_c,
                              const float* __restrict__ W_o, const float* __restrict__ fc_W,
                              const float* __restrict__ bg_i, const float* __restrict__ bg_c,
                              const float* __restrict__ bg_o,
                              const float* __restrict__ b_i, const float* __restrict__ b_c,
                              const float* __restrict__ b_o, const float* __restrict__ wc_o,
                              const float* __restrict__ fc_b,
                              short* __restrict__ wfrag, short* __restrict__ fcfrag,
                              float* __restrict__ bias) {
  int tid = blockIdx.x * blockDim.x + threadIdx.x;
  const int total1 = WFRAG_ELEMS;
  const int total2 = FCFRAG_ELEMS;
  for (int e = tid; e < total1 + total2 + HID + OUT_DIM; e += gridDim.x * blockDim.x) {
    if (e < total1) {
      // A-frag of GEMM1: D-row cidx of tile g, k=32s+8q+j, PERMUTED h, PRESCALED
      int j = e & 7, lane = (e >> 3) & 63, s = (e >> 9) & 1, t = e >> 10;
      int q = lane >> 4, cidx = lane & 15;
      int gate = t >> 3;                       // 0:W_i 1:W_c 2:W_o
      int g = t & 7;
      int h = hperm(g, cidx);
      int feat = 32 * s + 8 * q + j;
      const float* W = (gate == 0) ? W_i : ((gate == 1) ? W_c : W_o);
      float scale = (gate == 1) ? TWOLOG2E : -LOG2E;
      wfrag[e] = f2bf(W[feat * HID + h] * scale);
    } else if (e < total1 + total2) {
      // A-frag of GEMM2: A = fc_W^T (64x128), STANDARD hid = 32s+8q+j
      int e2 = e - total1;
      int j = e2 & 7, lane = (e2 >> 3) & 63, s = (e2 >> 9) & 3, t = e2 >> 11;
      int q = lane >> 4, cidx = lane & 15;
      int od = 16 * t + cidx;
      int hid = 32 * s + 8 * q + j;
      fcfrag[e2] = f2bf(fc_W[hid * OUT_DIM + od]);
    } else if (e < total1 + total2 + HID) {
      int p = e - total1 - total2;             // permuted storage index g*16+d
      int h = hperm(p >> 4, p & 15);
      bias[p]           = -LOG2E  * (bg_i[h] + b_i[h]);
      bias[HID + p]     = TWOLOG2E * (bg_c[h] + b_c[h]);
      bias[2 * HID + p] = -LOG2E  * (bg_o[h] + b_o[h]);
      bias[3 * HID + p] = -LOG2E  * wc_o[h];
    } else {
      int h2 = e - total1 - total2 - HID;
      bias[4 * HID + h2] = fc_b[h2];
    }
  }
}

// ---- fused main kernel: 1 wave per WG, 32 rows, no LDS, no barriers ----
__global__ __launch_bounds__(64, 4) void gclstm_fused(
    const float* __restrict__ x, const short* __restrict__ wfrag,
    const short* __restrict__ fcfrag, const float* __restrict__ bias,
    float* __restrict__ out) {
  const int lane = threadIdx.x;          // 0..63
  const int wid = blockIdx.x;            // 0..6249
  const size_t row0 = (size_t)wid * 32;
  const int q = lane >> 4, c = lane & 15;
  const short* wf = wfrag + lane * 8;
  const short* ff = fcfrag + lane * 8;

  union U { unsigned u[4]; short8 s8; };

  // x B-fragments (non-temporal: zero-reuse stream, keep out of L2)
  short8 bx[2][2];
#pragma unroll
  for (int m = 0; m < 2; ++m) {
    const float* xr = x + (row0 + 16 * m + c) * IN_DIM + 8 * q;
#pragma unroll
    for (int sk = 0; sk < 2; ++sk) {
      f32x4 f0 = __builtin_nontemporal_load((const f32x4*)(xr + 32 * sk));
      f32x4 f1 = __builtin_nontemporal_load((const f32x4*)(xr + 32 * sk + 4));
      U v;
      v.u[0] = cvt_pk_bf16(f0[0], f0[1]);
      v.u[1] = cvt_pk_bf16(f0[2], f0[3]);
      v.u[2] = cvt_pk_bf16(f1[0], f1[1]);
      v.u[3] = cvt_pk_bf16(f1[2], f1[3]);
      bx[m][sk] = v.s8;
    }
  }

  const float* Si  = bias;               // prescaled, permuted (index g*16+d)
  const float* Sc  = bias + HID;
  const float* So  = bias + 2 * HID;
  const float* Swc = bias + 3 * HID;
  const float* Fcb = bias + 4 * HID;     // standard od order

  // ---- Phase 1: 8 GEMM1 h-tiles + gates; H banked in 32 u32 regs ----
  unsigned hbuf[8][2][2];                // [g][m][word]
#pragma unroll
  for (int g = 0; g < 8; ++g) {
    const int p0 = g * 16 + 4 * q;
    f32x4 vbi = *(const f32x4*)(Si + p0);
    f32x4 vbc = *(const f32x4*)(Sc + p0);
    f32x4 vbo = *(const f32x4*)(So + p0);
    f32x4 vwc = *(const f32x4*)(Swc + p0);
    f32x4 acc[3][2];
#pragma unroll
    for (int m = 0; m < 2; ++m) { acc[0][m] = vbi; acc[1][m] = vbc; acc[2][m] = vbo; }
#pragma unroll
    for (int sk = 0; sk < 2; ++sk) {
      short8 ai = *(const short8*)(wf + ((g     ) * 2 + sk) * 512);
      short8 ac = *(const short8*)(wf + ((g +  8) * 2 + sk) * 512);
      short8 ao = *(const short8*)(wf + ((g + 16) * 2 + sk) * 512);
#pragma unroll
      for (int m = 0; m < 2; ++m) {
        acc[0][m] = __builtin_amdgcn_mfma_f32_16x16x32_bf16(ai, bx[m][sk], acc[0][m], 0, 0, 0);
        acc[1][m] = __builtin_amdgcn_mfma_f32_16x16x32_bf16(ac, bx[m][sk], acc[1][m], 0, 0, 0);
        acc[2][m] = __builtin_amdgcn_mfma_f32_16x16x32_bf16(ao, bx[m][sk], acc[2][m], 0, 0, 0);
      }
    }
    // gates (prescaled): ei=e^-zi, ec=e^2zc; C=(ec-1)*rcp((1+ei)(1+ec));
    // eo=e^-(zo+wc*C) via prescale; e2=e^2C; H=(e2-1)*rcp((1+eo)(1+e2)).
#pragma unroll
    for (int m = 0; m < 2; ++m) {
      f32x4 ei, ec;
#pragma unroll
      for (int r = 0; r < 4; ++r) { ei[r] = fexp2(acc[0][m][r]); ec[r] = fexp2(acc[1][m][r]); }
      f32x4 den1 = (ei + 1.0f) * (ec + 1.0f);
      f32x4 rd1;
#pragma unroll
      for (int r = 0; r < 4; ++r) rd1[r] = frcp(den1[r]);
      f32x4 C = (ec - 1.0f) * rd1;
      f32x4 s2 = acc[2][m] + vwc * C;
      f32x4 t2 = C * TWOLOG2E;
      f32x4 eo, e2;
#pragma unroll
      for (int r = 0; r < 4; ++r) { eo[r] = fexp2(s2[r]); e2[r] = fexp2(t2[r]); }
      f32x4 den2 = (eo + 1.0f) * (e2 + 1.0f);
      f32x4 rd2;
#pragma unroll
      for (int r = 0; r < 4; ++r) rd2[r] = frcp(den2[r]);
      f32x4 H = (e2 - 1.0f) * rd2;
      hbuf[g][m][0] = cvt_pk_bf16(H[0], H[1]);
      hbuf[g][m][1] = cvt_pk_bf16(H[2], H[3]);
    }
  }

  // ---- Phase 2: GEMM2 dense block; oacc init = fc bias (folded) ----
  f32x4 oacc[4][2];
#pragma unroll
  for (int t = 0; t < 4; ++t) {
    f32x4 fb = *(const f32x4*)(Fcb + 16 * t + 4 * q);
    oacc[t][0] = fb; oacc[t][1] = fb;
  }
#pragma unroll
  for (int s = 0; s < 4; ++s) {
#pragma unroll
    for (int m = 0; m < 2; ++m) {
      U bu;
      bu.u[0] = hbuf[2 * s][m][0];
      bu.u[1] = hbuf[2 * s + 1][m][0];
      bu.u[2] = hbuf[2 * s][m][1];
      bu.u[3] = hbuf[2 * s + 1][m][1];
#pragma unroll
      for (int t = 0; t < 4; ++t) {
        short8 af = *(const short8*)(ff + (t * 4 + s) * 512);
        oacc[t][m] = __builtin_amdgcn_mfma_f32_16x16x32_bf16(af, bu.s8, oacc[t][m], 0, 0, 0);
      }
    }
  }

  // ---- epilogue: non-temporal float4 stores (zero-reuse stream) ----
#pragma unroll
  for (int t = 0; t < 4; ++t) {
    const int od0 = 16 * t + 4 * q;
#pragma unroll
    for (int m = 0; m < 2; ++m) {
      __builtin_nontemporal_store(oacc[t][m],
          (f32x4*)(out + (row0 + 16 * m + c) * OUT_DIM + od0));
    }
  }
}

extern "C" void kernel_launch(void* const* d_in, const int* in_sizes, int n_in,
                              void* d_out, int out_size, void* d_ws, size_t ws_size,
                              hipStream_t stream) {
  (void)in_sizes; (void)n_in; (void)out_size; (void)ws_size;
  const float* x    = (const float*)d_in[0];
  const float* W_i  = (const float*)d_in[3];
  const float* W_c  = (const float*)d_in[5];
  const float* W_o  = (const float*)d_in[6];
  const float* bg_i = (const float*)d_in[11];
  const float* bg_c = (const float*)d_in[13];
  const float* bg_o = (const float*)d_in[14];
  const float* wc_o = (const float*)d_in[17];
  const float* b_i  = (const float*)d_in[18];
  const float* b_c  = (const float*)d_in[20];
  const float* b_o  = (const float*)d_in[21];
  const float* fc_W = (const float*)d_in[22];
  const float* fc_b = (const float*)d_in[23];

  short* wfrag  = (short*)d_ws;
  short* fcfrag = (short*)((char*)d_ws + FCFRAG_OFF);
  float* bias   = (float*)((char*)d_ws + BIAS_OFF);

  repack_kernel<<<dim3(64), dim3(256), 0, stream>>>(
      W_i, W_c, W_o, fc_W, bg_i, bg_c, bg_o, b_i, b_c, b_o, wc_o, fc_b,
      wfrag, fcfrag, bias);

  const int nwg = N_ROWS / 32;              // 6250 single-wave WGs
  gclstm_fused<<<dim3(nwg), dim3(64), 0, stream>>>(
      x, wfrag, fcfrag, bias, (float*)d_out);
}

// Round 15
// 56.295 us; speedup vs baseline: 1.0986x; 1.0305x over previous
//
#include <hip/hip_runtime.h>

// GCLSTM (K=1 Cheb, H0=C0=0) fused kernel for MI355X — v15.
// Math: i=sig(x@Wi+bi'), t=tanh(x@Wc+bc'), C=i*t, o=sig(x@Wo+bo'+wco*C),
//       out = (o*tanh(C)) @ fcW + fcb.  edge_index/batch/Wg_*/W_f unused.
// v15 = v9 + depth-2 software pipeline on the weight loads, in plain C++:
//     preload tile g+1's 6 frags while computing tile g (full unroll ->
//     SSA, copies vanish); prefetch s+1's 4 fcfrag frags in phase 2.
//     nt LOADS for x kept (v14: harmless); nt STORES dropped (v14: they
//     inflated WRITE 50->72MB, partial-line write-through). (64,4) only —
//     (64,2) was common to both NaN rounds. VGPR target <=~115.

typedef __attribute__((ext_vector_type(8))) short short8;
typedef __attribute__((ext_vector_type(4))) float f32x4;

#define N_ROWS 200000
#define IN_DIM 64
#define HID 128
#define OUT_DIM 64

#define LOG2E 1.44269504f
#define TWOLOG2E 2.88539008f

// ws layout (bytes)
#define WFRAG_ELEMS (24 * 2 * 64 * 8)   // 24576 bf16 = 49152 B
#define FCFRAG_OFF  49152               // WFRAG_ELEMS*2
#define FCFRAG_ELEMS (4 * 4 * 64 * 8)   // 8192 bf16 = 16384 B
#define BIAS_OFF    65536               // floats: si[128],sc[128],so[128],swc[128] (h-permuted, prescaled), fcb[64]

__device__ __forceinline__ short f2bf(float f) {
  unsigned u = __float_as_uint(f);
  u += 0x7FFFu + ((u >> 16) & 1u);   // RNE (repack only)
  return (short)(u >> 16);
}
__device__ __forceinline__ unsigned cvt_pk_bf16(float lo, float hi) {
  unsigned r;
  asm("v_cvt_pk_bf16_f32 %0, %1, %2" : "=v"(r) : "v"(lo), "v"(hi));
  return r;
}
__device__ __forceinline__ float fexp2(float z) { return __builtin_amdgcn_exp2f(z); }
__device__ __forceinline__ float frcp(float z)  { return __builtin_amdgcn_rcpf(z); }
// permuted global hid for GEMM1 tile g (0..7), D-row d (0..15)
__device__ __forceinline__ int hperm(int g, int d) {
  return 32 * (g >> 1) + 2 * (g & 1) + 8 * (d >> 2) + 4 * ((d >> 1) & 1) + (d & 1);
}

// ---- repack: weights -> bf16 MFMA A-fragments (PRESCALED), biases fp32 ----
__global__ void repack_kernel(const float* __restrict__ W_i, const float* __restrict__ W_c,
                              const float* __restrict__ W_o, const float* __restrict__ fc_W,
                              const float* __restrict__ bg_i, const float* __restrict__ bg_c,
                              const float* __restrict__ bg_o,
                              const float* __restrict__ b_i, const float* __restrict__ b_c,
                              const float* __restrict__ b_o, const float* __restrict__ wc_o,
                              const float* __restrict__ fc_b,
                              short* __restrict__ wfrag, short* __restrict__ fcfrag,
                              float* __restrict__ bias) {
  int tid = blockIdx.x * blockDim.x + threadIdx.x;
  const int total1 = WFRAG_ELEMS;
  const int total2 = FCFRAG_ELEMS;
  for (int e = tid; e < total1 + total2 + HID + OUT_DIM; e += gridDim.x * blockDim.x) {
    if (e < total1) {
      // A-frag of GEMM1: D-row cidx of tile g, k=32s+8q+j, PERMUTED h, PRESCALED
      int j = e & 7, lane = (e >> 3) & 63, s = (e >> 9) & 1, t = e >> 10;
      int q = lane >> 4, cidx = lane & 15;
      int gate = t >> 3;                       // 0:W_i 1:W_c 2:W_o
      int g = t & 7;
      int h = hperm(g, cidx);
      int feat = 32 * s + 8 * q + j;
      const float* W = (gate == 0) ? W_i : ((gate == 1) ? W_c : W_o);
      float scale = (gate == 1) ? TWOLOG2E : -LOG2E;
      wfrag[e] = f2bf(W[feat * HID + h] * scale);
    } else if (e < total1 + total2) {
      // A-frag of GEMM2: A = fc_W^T (64x128), STANDARD hid = 32s+8q+j
      int e2 = e - total1;
      int j = e2 & 7, lane = (e2 >> 3) & 63, s = (e2 >> 9) & 3, t = e2 >> 11;
      int q = lane >> 4, cidx = lane & 15;
      int od = 16 * t + cidx;
      int hid = 32 * s + 8 * q + j;
      fcfrag[e2] = f2bf(fc_W[hid * OUT_DIM + od]);
    } else if (e < total1 + total2 + HID) {
      int p = e - total1 - total2;             // permuted storage index g*16+d
      int h = hperm(p >> 4, p & 15);
      bias[p]           = -LOG2E  * (bg_i[h] + b_i[h]);
      bias[HID + p]     = TWOLOG2E * (bg_c[h] + b_c[h]);
      bias[2 * HID + p] = -LOG2E  * (bg_o[h] + b_o[h]);
      bias[3 * HID + p] = -LOG2E  * wc_o[h];
    } else {
      int h2 = e - total1 - total2 - HID;
      bias[4 * HID + h2] = fc_b[h2];
    }
  }
}

// ---- fused main kernel: 1 wave per WG, 32 rows, pipelined loads ----
__global__ __launch_bounds__(64, 4) void gclstm_fused(
    const float* __restrict__ x, const short* __restrict__ wfrag,
    const short* __restrict__ fcfrag, const float* __restrict__ bias,
    float* __restrict__ out) {
  const int lane = threadIdx.x;          // 0..63
  const int wid = blockIdx.x;            // 0..6249
  const size_t row0 = (size_t)wid * 32;
  const int q = lane >> 4, c = lane & 15;
  const short* wf = wfrag + lane * 8;
  const short* ff = fcfrag + lane * 8;

  union U { unsigned u[4]; short8 s8; };

  // x B-fragments (nt loads: zero-reuse stream, keep out of L2)
  short8 bx[2][2];
#pragma unroll
  for (int m = 0; m < 2; ++m) {
    const float* xr = x + (row0 + 16 * m + c) * IN_DIM + 8 * q;
#pragma unroll
    for (int sk = 0; sk < 2; ++sk) {
      f32x4 f0 = __builtin_nontemporal_load((const f32x4*)(xr + 32 * sk));
      f32x4 f1 = __builtin_nontemporal_load((const f32x4*)(xr + 32 * sk + 4));
      U v;
      v.u[0] = cvt_pk_bf16(f0[0], f0[1]);
      v.u[1] = cvt_pk_bf16(f0[2], f0[3]);
      v.u[2] = cvt_pk_bf16(f1[0], f1[1]);
      v.u[3] = cvt_pk_bf16(f1[2], f1[3]);
      bx[m][sk] = v.s8;
    }
  }

  const float* Si  = bias;               // prescaled, permuted (index g*16+d)
  const float* Sc  = bias + HID;
  const float* So  = bias + 2 * HID;
  const float* Swc = bias + 3 * HID;
  const float* Fcb = bias + 4 * HID;     // standard od order

  // ---- Phase 1: depth-2 pipelined over the 8 h-tiles ----
  unsigned hbuf[8][2][2];                // [g][m][word]
  short8 w0_0, w0_1, w1_0, w1_1, w2_0, w2_1;   // current tile's 6 frags
  w0_0 = *(const short8*)(wf + ((0     ) * 2 + 0) * 512);
  w0_1 = *(const short8*)(wf + ((0     ) * 2 + 1) * 512);
  w1_0 = *(const short8*)(wf + ((0 +  8) * 2 + 0) * 512);
  w1_1 = *(const short8*)(wf + ((0 +  8) * 2 + 1) * 512);
  w2_0 = *(const short8*)(wf + ((0 + 16) * 2 + 0) * 512);
  w2_1 = *(const short8*)(wf + ((0 + 16) * 2 + 1) * 512);
#pragma unroll
  for (int g = 0; g < 8; ++g) {
    // issue next tile's loads BEFORE consuming current tile (latency overlap)
    short8 n0_0, n0_1, n1_0, n1_1, n2_0, n2_1;
    if (g < 7) {
      const int gn = g + 1;
      n0_0 = *(const short8*)(wf + ((gn     ) * 2 + 0) * 512);
      n0_1 = *(const short8*)(wf + ((gn     ) * 2 + 1) * 512);
      n1_0 = *(const short8*)(wf + ((gn +  8) * 2 + 0) * 512);
      n1_1 = *(const short8*)(wf + ((gn +  8) * 2 + 1) * 512);
      n2_0 = *(const short8*)(wf + ((gn + 16) * 2 + 0) * 512);
      n2_1 = *(const short8*)(wf + ((gn + 16) * 2 + 1) * 512);
    }
    const int p0 = g * 16 + 4 * q;
    f32x4 vbi = *(const f32x4*)(Si + p0);
    f32x4 vbc = *(const f32x4*)(Sc + p0);
    f32x4 vbo = *(const f32x4*)(So + p0);
    f32x4 vwc = *(const f32x4*)(Swc + p0);
    f32x4 acc[3][2];
#pragma unroll
    for (int m = 0; m < 2; ++m) { acc[0][m] = vbi; acc[1][m] = vbc; acc[2][m] = vbo; }
#pragma unroll
    for (int m = 0; m < 2; ++m) {
      acc[0][m] = __builtin_amdgcn_mfma_f32_16x16x32_bf16(w0_0, bx[m][0], acc[0][m], 0, 0, 0);
      acc[1][m] = __builtin_amdgcn_mfma_f32_16x16x32_bf16(w1_0, bx[m][0], acc[1][m], 0, 0, 0);
      acc[2][m] = __builtin_amdgcn_mfma_f32_16x16x32_bf16(w2_0, bx[m][0], acc[2][m], 0, 0, 0);
      acc[0][m] = __builtin_amdgcn_mfma_f32_16x16x32_bf16(w0_1, bx[m][1], acc[0][m], 0, 0, 0);
      acc[1][m] = __builtin_amdgcn_mfma_f32_16x16x32_bf16(w1_1, bx[m][1], acc[1][m], 0, 0, 0);
      acc[2][m] = __builtin_amdgcn_mfma_f32_16x16x32_bf16(w2_1, bx[m][1], acc[2][m], 0, 0, 0);
    }
    // gates (prescaled): ei=e^-zi, ec=e^2zc; C=(ec-1)*rcp((1+ei)(1+ec));
    // eo=e^-(zo+wc*C) via prescale; e2=e^2C; H=(e2-1)*rcp((1+eo)(1+e2)).
#pragma unroll
    for (int m = 0; m < 2; ++m) {
      f32x4 ei, ec;
#pragma unroll
      for (int r = 0; r < 4; ++r) { ei[r] = fexp2(acc[0][m][r]); ec[r] = fexp2(acc[1][m][r]); }
      f32x4 den1 = (ei + 1.0f) * (ec + 1.0f);
      f32x4 rd1;
#pragma unroll
      for (int r = 0; r < 4; ++r) rd1[r] = frcp(den1[r]);
      f32x4 C = (ec - 1.0f) * rd1;
      f32x4 s2 = acc[2][m] + vwc * C;
      f32x4 t2 = C * TWOLOG2E;
      f32x4 eo, e2;
#pragma unroll
      for (int r = 0; r < 4; ++r) { eo[r] = fexp2(s2[r]); e2[r] = fexp2(t2[r]); }
      f32x4 den2 = (eo + 1.0f) * (e2 + 1.0f);
      f32x4 rd2;
#pragma unroll
      for (int r = 0; r < 4; ++r) rd2[r] = frcp(den2[r]);
      f32x4 H = (e2 - 1.0f) * rd2;
      hbuf[g][m][0] = cvt_pk_bf16(H[0], H[1]);
      hbuf[g][m][1] = cvt_pk_bf16(H[2], H[3]);
    }
    if (g < 7) {   // rotate (full unroll -> SSA renaming, no real moves)
      w0_0 = n0_0; w0_1 = n0_1; w1_0 = n1_0; w1_1 = n1_1; w2_0 = n2_0; w2_1 = n2_1;
    }
  }

  // ---- Phase 2: depth-2 pipelined over s; oacc init = fc bias ----
  f32x4 oacc[4][2];
#pragma unroll
  for (int t = 0; t < 4; ++t) {
    f32x4 fb = *(const f32x4*)(Fcb + 16 * t + 4 * q);
    oacc[t][0] = fb; oacc[t][1] = fb;
  }
  short8 afc[4], afn[4];
#pragma unroll
  for (int t = 0; t < 4; ++t) afc[t] = *(const short8*)(ff + (t * 4 + 0) * 512);
#pragma unroll
  for (int s = 0; s < 4; ++s) {
    if (s < 3) {
#pragma unroll
      for (int t = 0; t < 4; ++t) afn[t] = *(const short8*)(ff + (t * 4 + s + 1) * 512);
    }
#pragma unroll
    for (int m = 0; m < 2; ++m) {
      U bu;
      bu.u[0] = hbuf[2 * s][m][0];
      bu.u[1] = hbuf[2 * s + 1][m][0];
      bu.u[2] = hbuf[2 * s][m][1];
      bu.u[3] = hbuf[2 * s + 1][m][1];
#pragma unroll
      for (int t = 0; t < 4; ++t)
        oacc[t][m] = __builtin_amdgcn_mfma_f32_16x16x32_bf16(afc[t], bu.s8, oacc[t][m], 0, 0, 0);
    }
    if (s < 3) {
#pragma unroll
      for (int t = 0; t < 4; ++t) afc[t] = afn[t];
    }
  }

  // ---- epilogue: coalesced float4 stores (normal, full-line) ----
#pragma unroll
  for (int t = 0; t < 4; ++t) {
    const int od0 = 16 * t + 4 * q;
#pragma unroll
    for (int m = 0; m < 2; ++m) {
      *(f32x4*)(out + (row0 + 16 * m + c) * OUT_DIM + od0) = oacc[t][m];
    }
  }
}

extern "C" void kernel_launch(void* const* d_in, const int* in_sizes, int n_in,
                              void* d_out, int out_size, void* d_ws, size_t ws_size,
                              hipStream_t stream) {
  (void)in_sizes; (void)n_in; (void)out_size; (void)ws_size;
  const float* x    = (const float*)d_in[0];
  const float* W_i  = (const float*)d_in[3];
  const float* W_c  = (const float*)d_in[5];
  const float* W_o  = (const float*)d_in[6];
  const float* bg_i = (const float*)d_in[11];
  const float* bg_c = (const float*)d_in[13];
  const float* bg_o = (const float*)d_in[14];
  const float* wc_o = (const float*)d_in[17];
  const float* b_i  = (const float*)d_in[18];
  const float* b_c  = (const float*)d_in[20];
  const float* b_o  = (const float*)d_in[21];
  const float* fc_W = (const float*)d_in[22];
  const float* fc_b = (const float*)d_in[23];

  short* wfrag  = (short*)d_ws;
  short* fcfrag = (short*)((char*)d_ws + FCFRAG_OFF);
  float* bias   = (float*)((char*)d_ws + BIAS_OFF);

  repack_kernel<<<dim3(64), dim3(256), 0, stream>>>(
      W_i, W_c, W_o, fc_W, bg_i, bg_c, bg_o, b_i, b_c, b_o, wc_o, fc_b,
      wfrag, fcfrag, bias);

  const int nwg = N_ROWS / 32;              // 6250 single-wave WGs
  gclstm_fused<<<dim3(nwg), dim3(64), 0, stream>>>(
      x, wfrag, fcfrag, bias, (float*)d_out);
}

// Round 16
// 48.981 us; speedup vs baseline: 1.2626x; 1.1493x over previous
//
#include <hip/hip_runtime.h>

// GCLSTM (K=1 Cheb, H0=C0=0) fused kernel for MI355X — v16.
// Math: i=sig(x@Wi+bi'), t=tanh(x@Wc+bc'), C=i*t, o=sig(x@Wo+bo'+wco*C),
//       out = (o*tanh(C)) @ fcW + fcb.  edge_index/batch/Wg_*/W_f unused.
// v16 = v9 (best: 49.5us) with ONE change: accumulators init to ZERO and
//     bias/fc-bias added AFTER the MFMA blocks. The bias loads still issue
//     at iteration top but no longer gate the MFMAs -> 36 dependent loads
//     leave the per-wave serial chain. No nt, no pipeline, no asm pins.

typedef __attribute__((ext_vector_type(8))) short short8;
typedef __attribute__((ext_vector_type(4))) float f32x4;

#define N_ROWS 200000
#define IN_DIM 64
#define HID 128
#define OUT_DIM 64

#define LOG2E 1.44269504f
#define TWOLOG2E 2.88539008f

// ws layout (bytes)
#define WFRAG_ELEMS (24 * 2 * 64 * 8)   // 24576 bf16 = 49152 B
#define FCFRAG_OFF  49152               // WFRAG_ELEMS*2
#define FCFRAG_ELEMS (4 * 4 * 64 * 8)   // 8192 bf16 = 16384 B
#define BIAS_OFF    65536               // floats: si[128],sc[128],so[128],swc[128] (h-permuted, prescaled), fcb[64]

__device__ __forceinline__ short f2bf(float f) {
  unsigned u = __float_as_uint(f);
  u += 0x7FFFu + ((u >> 16) & 1u);   // RNE (repack only)
  return (short)(u >> 16);
}
__device__ __forceinline__ unsigned cvt_pk_bf16(float lo, float hi) {
  unsigned r;
  asm("v_cvt_pk_bf16_f32 %0, %1, %2" : "=v"(r) : "v"(lo), "v"(hi));
  return r;
}
__device__ __forceinline__ float fexp2(float z) { return __builtin_amdgcn_exp2f(z); }
__device__ __forceinline__ float frcp(float z)  { return __builtin_amdgcn_rcpf(z); }
// permuted global hid for GEMM1 tile g (0..7), D-row d (0..15)
__device__ __forceinline__ int hperm(int g, int d) {
  return 32 * (g >> 1) + 2 * (g & 1) + 8 * (d >> 2) + 4 * ((d >> 1) & 1) + (d & 1);
}

// ---- repack: weights -> bf16 MFMA A-fragments (PRESCALED), biases fp32 ----
__global__ void repack_kernel(const float* __restrict__ W_i, const float* __restrict__ W_c,
                              const float* __restrict__ W_o, const float* __restrict__ fc_W,
                              const float* __restrict__ bg_i, const float* __restrict__ bg_c,
                              const float* __restrict__ bg_o,
                              const float* __restrict__ b_i, const float* __restrict__ b_c,
                              const float* __restrict__ b_o, const float* __restrict__ wc_o,
                              const float* __restrict__ fc_b,
                              short* __restrict__ wfrag, short* __restrict__ fcfrag,
                              float* __restrict__ bias) {
  int tid = blockIdx.x * blockDim.x + threadIdx.x;
  const int total1 = WFRAG_ELEMS;
  const int total2 = FCFRAG_ELEMS;
  for (int e = tid; e < total1 + total2 + HID + OUT_DIM; e += gridDim.x * blockDim.x) {
    if (e < total1) {
      // A-frag of GEMM1: D-row cidx of tile g, k=32s+8q+j, PERMUTED h, PRESCALED
      int j = e & 7, lane = (e >> 3) & 63, s = (e >> 9) & 1, t = e >> 10;
      int q = lane >> 4, cidx = lane & 15;
      int gate = t >> 3;                       // 0:W_i 1:W_c 2:W_o
      int g = t & 7;
      int h = hperm(g, cidx);
      int feat = 32 * s + 8 * q + j;
      const float* W = (gate == 0) ? W_i : ((gate == 1) ? W_c : W_o);
      float scale = (gate == 1) ? TWOLOG2E : -LOG2E;
      wfrag[e] = f2bf(W[feat * HID + h] * scale);
    } else if (e < total1 + total2) {
      // A-frag of GEMM2: A = fc_W^T (64x128), STANDARD hid = 32s+8q+j
      int e2 = e - total1;
      int j = e2 & 7, lane = (e2 >> 3) & 63, s = (e2 >> 9) & 3, t = e2 >> 11;
      int q = lane >> 4, cidx = lane & 15;
      int od = 16 * t + cidx;
      int hid = 32 * s + 8 * q + j;
      fcfrag[e2] = f2bf(fc_W[hid * OUT_DIM + od]);
    } else if (e < total1 + total2 + HID) {
      int p = e - total1 - total2;             // permuted storage index g*16+d
      int h = hperm(p >> 4, p & 15);
      bias[p]           = -LOG2E  * (bg_i[h] + b_i[h]);
      bias[HID + p]     = TWOLOG2E * (bg_c[h] + b_c[h]);
      bias[2 * HID + p] = -LOG2E  * (bg_o[h] + b_o[h]);
      bias[3 * HID + p] = -LOG2E  * wc_o[h];
    } else {
      int h2 = e - total1 - total2 - HID;
      bias[4 * HID + h2] = fc_b[h2];
    }
  }
}

// ---- fused main kernel: 1 wave per WG, 32 rows, no LDS, no barriers ----
__global__ __launch_bounds__(64, 4) void gclstm_fused(
    const float* __restrict__ x, const short* __restrict__ wfrag,
    const short* __restrict__ fcfrag, const float* __restrict__ bias,
    float* __restrict__ out) {
  const int lane = threadIdx.x;          // 0..63
  const int wid = blockIdx.x;            // 0..6249
  const size_t row0 = (size_t)wid * 32;
  const int q = lane >> 4, c = lane & 15;
  const short* wf = wfrag + lane * 8;
  const short* ff = fcfrag + lane * 8;

  union U { unsigned u[4]; short8 s8; };

  // x B-fragments: B = x^T; lane supplies col (row row0+16m+c), k=32sk+8q+j
  short8 bx[2][2];
#pragma unroll
  for (int m = 0; m < 2; ++m) {
    const float* xr = x + (row0 + 16 * m + c) * IN_DIM + 8 * q;
#pragma unroll
    for (int sk = 0; sk < 2; ++sk) {
      f32x4 f0 = *(const f32x4*)(xr + 32 * sk);
      f32x4 f1 = *(const f32x4*)(xr + 32 * sk + 4);
      U v;
      v.u[0] = cvt_pk_bf16(f0[0], f0[1]);
      v.u[1] = cvt_pk_bf16(f0[2], f0[3]);
      v.u[2] = cvt_pk_bf16(f1[0], f1[1]);
      v.u[3] = cvt_pk_bf16(f1[2], f1[3]);
      bx[m][sk] = v.s8;
    }
  }

  const float* Si  = bias;               // prescaled, permuted (index g*16+d)
  const float* Sc  = bias + HID;
  const float* So  = bias + 2 * HID;
  const float* Swc = bias + 3 * HID;
  const float* Fcb = bias + 4 * HID;     // standard od order

  // ---- Phase 1: 8 GEMM1 h-tiles + gates; H banked in 32 u32 regs ----
  unsigned hbuf[8][2][2];                // [g][m][word]
#pragma unroll
  for (int g = 0; g < 8; ++g) {
    const int p0 = g * 16 + 4 * q;
    // bias loads issue here but are consumed AFTER the MFMA block
    f32x4 vbi = *(const f32x4*)(Si + p0);
    f32x4 vbc = *(const f32x4*)(Sc + p0);
    f32x4 vbo = *(const f32x4*)(So + p0);
    f32x4 vwc = *(const f32x4*)(Swc + p0);
    f32x4 acc[3][2];
#pragma unroll
    for (int m = 0; m < 2; ++m) {
      acc[0][m] = (f32x4){0.f, 0.f, 0.f, 0.f};
      acc[1][m] = (f32x4){0.f, 0.f, 0.f, 0.f};
      acc[2][m] = (f32x4){0.f, 0.f, 0.f, 0.f};
    }
#pragma unroll
    for (int sk = 0; sk < 2; ++sk) {
      short8 ai = *(const short8*)(wf + ((g     ) * 2 + sk) * 512);
      short8 ac = *(const short8*)(wf + ((g +  8) * 2 + sk) * 512);
      short8 ao = *(const short8*)(wf + ((g + 16) * 2 + sk) * 512);
#pragma unroll
      for (int m = 0; m < 2; ++m) {
        acc[0][m] = __builtin_amdgcn_mfma_f32_16x16x32_bf16(ai, bx[m][sk], acc[0][m], 0, 0, 0);
        acc[1][m] = __builtin_amdgcn_mfma_f32_16x16x32_bf16(ac, bx[m][sk], acc[1][m], 0, 0, 0);
        acc[2][m] = __builtin_amdgcn_mfma_f32_16x16x32_bf16(ao, bx[m][sk], acc[2][m], 0, 0, 0);
      }
    }
    // gates (prescaled, bias added post-MFMA): ei=e^-zi, ec=e^2zc;
    // C=(ec-1)*rcp((1+ei)(1+ec)); eo=e^-(zo+wc*C); e2=e^2C;
    // H=(e2-1)*rcp((1+eo)(1+e2)).
#pragma unroll
    for (int m = 0; m < 2; ++m) {
      f32x4 z0 = acc[0][m] + vbi;
      f32x4 z1 = acc[1][m] + vbc;
      f32x4 ei, ec;
#pragma unroll
      for (int r = 0; r < 4; ++r) { ei[r] = fexp2(z0[r]); ec[r] = fexp2(z1[r]); }
      f32x4 den1 = (ei + 1.0f) * (ec + 1.0f);
      f32x4 rd1;
#pragma unroll
      for (int r = 0; r < 4; ++r) rd1[r] = frcp(den1[r]);
      f32x4 C = (ec - 1.0f) * rd1;
      f32x4 s2 = (acc[2][m] + vbo) + vwc * C;
      f32x4 t2 = C * TWOLOG2E;
      f32x4 eo, e2;
#pragma unroll
      for (int r = 0; r < 4; ++r) { eo[r] = fexp2(s2[r]); e2[r] = fexp2(t2[r]); }
      f32x4 den2 = (eo + 1.0f) * (e2 + 1.0f);
      f32x4 rd2;
#pragma unroll
      for (int r = 0; r < 4; ++r) rd2[r] = frcp(den2[r]);
      f32x4 H = (e2 - 1.0f) * rd2;
      hbuf[g][m][0] = cvt_pk_bf16(H[0], H[1]);
      hbuf[g][m][1] = cvt_pk_bf16(H[2], H[3]);
    }
  }

  // ---- Phase 2: GEMM2 dense block; oacc init ZERO, fc bias added at store ----
  f32x4 oacc[4][2];
#pragma unroll
  for (int t = 0; t < 4; ++t) {
    oacc[t][0] = (f32x4){0.f, 0.f, 0.f, 0.f};
    oacc[t][1] = (f32x4){0.f, 0.f, 0.f, 0.f};
  }
#pragma unroll
  for (int s = 0; s < 4; ++s) {
#pragma unroll
    for (int m = 0; m < 2; ++m) {
      U bu;
      bu.u[0] = hbuf[2 * s][m][0];
      bu.u[1] = hbuf[2 * s + 1][m][0];
      bu.u[2] = hbuf[2 * s][m][1];
      bu.u[3] = hbuf[2 * s + 1][m][1];
#pragma unroll
      for (int t = 0; t < 4; ++t) {
        short8 af = *(const short8*)(ff + (t * 4 + s) * 512);
        oacc[t][m] = __builtin_amdgcn_mfma_f32_16x16x32_bf16(af, bu.s8, oacc[t][m], 0, 0, 0);
      }
    }
  }

  // ---- epilogue: add fc bias, coalesced float4 stores ----
#pragma unroll
  for (int t = 0; t < 4; ++t) {
    const int od0 = 16 * t + 4 * q;
    f32x4 fb = *(const f32x4*)(Fcb + od0);
#pragma unroll
    for (int m = 0; m < 2; ++m) {
      f32x4 v = oacc[t][m] + fb;
      *(f32x4*)(out + (row0 + 16 * m + c) * OUT_DIM + od0) = v;
    }
  }
}

extern "C" void kernel_launch(void* const* d_in, const int* in_sizes, int n_in,
                              void* d_out, int out_size, void* d_ws, size_t ws_size,
                              hipStream_t stream) {
  (void)in_sizes; (void)n_in; (void)out_size; (void)ws_size;
  const float* x    = (const float*)d_in[0];
  const float* W_i  = (const float*)d_in[3];
  const float* W_c  = (const float*)d_in[5];
  const float* W_o  = (const float*)d_in[6];
  const float* bg_i = (const float*)d_in[11];
  const float* bg_c = (const float*)d_in[13];
  const float* bg_o = (const float*)d_in[14];
  const float* wc_o = (const float*)d_in[17];
  const float* b_i  = (const float*)d_in[18];
  const float* b_c  = (const float*)d_in[20];
  const float* b_o  = (const float*)d_in[21];
  const float* fc_W = (const float*)d_in[22];
  const float* fc_b = (const float*)d_in[23];

  short* wfrag  = (short*)d_ws;
  short* fcfrag = (short*)((char*)d_ws + FCFRAG_OFF);
  float* bias   = (float*)((char*)d_ws + BIAS_OFF);

  repack_kernel<<<dim3(64), dim3(256), 0, stream>>>(
      W_i, W_c, W_o, fc_W, bg_i, bg_c, bg_o, b_i, b_c, b_o, wc_o, fc_b,
      wfrag, fcfrag, bias);

  const int nwg = N_ROWS / 32;              // 6250 single-wave WGs
  gclstm_fused<<<dim3(nwg), dim3(64), 0, stream>>>(
      x, wfrag, fcfrag, bias, (float*)d_out);
}

// Round 17
// 47.892 us; speedup vs baseline: 1.2913x; 1.0227x over previous
//
#include <hip/hip_runtime.h>

// GCLSTM (K=1 Cheb, H0=C0=0) fused kernel for MI355X — v17.
// Math: i=sig(x@Wi+bi'), t=sig/tanh forms via exp2 (prescaled), C=i*t,
//       o=sig(x@Wo+bo'+wco*C), out = (o*tanh(C)) @ fcW + fcb.
// v17 = v16 (best, 48.98us) + chunked weight-load BURSTS with input-only
//     asm materialization (rule-#17 idiom; v13's "+v" read-write pins were
//     the NaN suspect). Phase 1: 4 chunks x {12 loads -> pin -> 2 h-tiles}.
//     Phase 2: 2 halves x {8 fc loads -> pin -> 2 s-blocks}. ~12 loads in
//     flight vs compiler's 2-3. launch_bounds(64,3): ~168 VGPR budget.

typedef __attribute__((ext_vector_type(8))) short short8;
typedef __attribute__((ext_vector_type(4))) float f32x4;

#define N_ROWS 200000
#define IN_DIM 64
#define HID 128
#define OUT_DIM 64

#define LOG2E 1.44269504f
#define TWOLOG2E 2.88539008f

// ws layout (bytes)
#define WFRAG_ELEMS (24 * 2 * 64 * 8)   // 24576 bf16 = 49152 B
#define FCFRAG_OFF  49152               // WFRAG_ELEMS*2
#define FCFRAG_ELEMS (4 * 4 * 64 * 8)   // 8192 bf16 = 16384 B
#define BIAS_OFF    65536               // floats: si[128],sc[128],so[128],swc[128] (h-permuted, prescaled), fcb[64]

__device__ __forceinline__ short f2bf(float f) {
  unsigned u = __float_as_uint(f);
  u += 0x7FFFu + ((u >> 16) & 1u);   // RNE (repack only)
  return (short)(u >> 16);
}
__device__ __forceinline__ unsigned cvt_pk_bf16(float lo, float hi) {
  unsigned r;
  asm("v_cvt_pk_bf16_f32 %0, %1, %2" : "=v"(r) : "v"(lo), "v"(hi));
  return r;
}
__device__ __forceinline__ float fexp2(float z) { return __builtin_amdgcn_exp2f(z); }
__device__ __forceinline__ float frcp(float z)  { return __builtin_amdgcn_rcpf(z); }
// permuted global hid for GEMM1 tile g (0..7), D-row d (0..15)
__device__ __forceinline__ int hperm(int g, int d) {
  return 32 * (g >> 1) + 2 * (g & 1) + 8 * (d >> 2) + 4 * ((d >> 1) & 1) + (d & 1);
}

// ---- repack: weights -> bf16 MFMA A-fragments (PRESCALED), biases fp32 ----
__global__ void repack_kernel(const float* __restrict__ W_i, const float* __restrict__ W_c,
                              const float* __restrict__ W_o, const float* __restrict__ fc_W,
                              const float* __restrict__ bg_i, const float* __restrict__ bg_c,
                              const float* __restrict__ bg_o,
                              const float* __restrict__ b_i, const float* __restrict__ b_c,
                              const float* __restrict__ b_o, const float* __restrict__ wc_o,
                              const float* __restrict__ fc_b,
                              short* __restrict__ wfrag, short* __restrict__ fcfrag,
                              float* __restrict__ bias) {
  int tid = blockIdx.x * blockDim.x + threadIdx.x;
  const int total1 = WFRAG_ELEMS;
  const int total2 = FCFRAG_ELEMS;
  for (int e = tid; e < total1 + total2 + HID + OUT_DIM; e += gridDim.x * blockDim.x) {
    if (e < total1) {
      // A-frag of GEMM1: D-row cidx of tile g, k=32s+8q+j, PERMUTED h, PRESCALED
      int j = e & 7, lane = (e >> 3) & 63, s = (e >> 9) & 1, t = e >> 10;
      int q = lane >> 4, cidx = lane & 15;
      int gate = t >> 3;                       // 0:W_i 1:W_c 2:W_o
      int g = t & 7;
      int h = hperm(g, cidx);
      int feat = 32 * s + 8 * q + j;
      const float* W = (gate == 0) ? W_i : ((gate == 1) ? W_c : W_o);
      float scale = (gate == 1) ? TWOLOG2E : -LOG2E;
      wfrag[e] = f2bf(W[feat * HID + h] * scale);
    } else if (e < total1 + total2) {
      // A-frag of GEMM2: A = fc_W^T (64x128), STANDARD hid = 32s+8q+j
      int e2 = e - total1;
      int j = e2 & 7, lane = (e2 >> 3) & 63, s = (e2 >> 9) & 3, t = e2 >> 11;
      int q = lane >> 4, cidx = lane & 15;
      int od = 16 * t + cidx;
      int hid = 32 * s + 8 * q + j;
      fcfrag[e2] = f2bf(fc_W[hid * OUT_DIM + od]);
    } else if (e < total1 + total2 + HID) {
      int p = e - total1 - total2;             // permuted storage index g*16+d
      int h = hperm(p >> 4, p & 15);
      bias[p]           = -LOG2E  * (bg_i[h] + b_i[h]);
      bias[HID + p]     = TWOLOG2E * (bg_c[h] + b_c[h]);
      bias[2 * HID + p] = -LOG2E  * (bg_o[h] + b_o[h]);
      bias[3 * HID + p] = -LOG2E  * wc_o[h];
    } else {
      int h2 = e - total1 - total2 - HID;
      bias[4 * HID + h2] = fc_b[h2];
    }
  }
}

// ---- fused main kernel: 1 wave per WG, 32 rows, burst-pipelined loads ----
__global__ __launch_bounds__(64, 3) void gclstm_fused(
    const float* __restrict__ x, const short* __restrict__ wfrag,
    const short* __restrict__ fcfrag, const float* __restrict__ bias,
    float* __restrict__ out) {
  const int lane = threadIdx.x;          // 0..63
  const int wid = blockIdx.x;            // 0..6249
  const size_t row0 = (size_t)wid * 32;
  const int q = lane >> 4, c = lane & 15;
  const short* wf = wfrag + lane * 8;
  const short* ff = fcfrag + lane * 8;

  union U { unsigned u[4]; short8 s8; };

  // x B-fragments: B = x^T; lane supplies col (row row0+16m+c), k=32sk+8q+j
  short8 bx[2][2];
#pragma unroll
  for (int m = 0; m < 2; ++m) {
    const float* xr = x + (row0 + 16 * m + c) * IN_DIM + 8 * q;
#pragma unroll
    for (int sk = 0; sk < 2; ++sk) {
      f32x4 f0 = *(const f32x4*)(xr + 32 * sk);
      f32x4 f1 = *(const f32x4*)(xr + 32 * sk + 4);
      U v;
      v.u[0] = cvt_pk_bf16(f0[0], f0[1]);
      v.u[1] = cvt_pk_bf16(f0[2], f0[3]);
      v.u[2] = cvt_pk_bf16(f1[0], f1[1]);
      v.u[3] = cvt_pk_bf16(f1[2], f1[3]);
      bx[m][sk] = v.s8;
    }
  }

  const float* Si  = bias;               // prescaled, permuted (index g*16+d)
  const float* Sc  = bias + HID;
  const float* So  = bias + 2 * HID;
  const float* Swc = bias + 3 * HID;
  const float* Fcb = bias + 4 * HID;     // standard od order

  // ---- Phase 1: 4 chunks x {12-load burst -> pin -> 2 h-tiles} ----
  unsigned hbuf[8][2][2];                // [g][m][word]
#pragma unroll
  for (int ch = 0; ch < 4; ++ch) {
    short8 w[2][3][2];                   // [gg][gate][sk] = 48 VGPR
#pragma unroll
    for (int gg = 0; gg < 2; ++gg) {
      const int g = ch * 2 + gg;
      w[gg][0][0] = *(const short8*)(wf + ((g     ) * 2 + 0) * 512);
      w[gg][0][1] = *(const short8*)(wf + ((g     ) * 2 + 1) * 512);
      w[gg][1][0] = *(const short8*)(wf + ((g +  8) * 2 + 0) * 512);
      w[gg][1][1] = *(const short8*)(wf + ((g +  8) * 2 + 1) * 512);
      w[gg][2][0] = *(const short8*)(wf + ((g + 16) * 2 + 0) * 512);
      w[gg][2][1] = *(const short8*)(wf + ((g + 16) * 2 + 1) * 512);
    }
    // materialize: all 12 loads issue before the first MFMA consumes any
    // (input-only keep-alive pins — rule #17 idiom, no mutation)
#pragma unroll
    for (int gg = 0; gg < 2; ++gg)
#pragma unroll
      for (int gt = 0; gt < 3; ++gt)
        asm volatile("" :: "v"(w[gg][gt][0]), "v"(w[gg][gt][1]));

#pragma unroll
    for (int gg = 0; gg < 2; ++gg) {
      const int g = ch * 2 + gg;
      const int p0 = g * 16 + 4 * q;
      f32x4 vbi = *(const f32x4*)(Si + p0);
      f32x4 vbc = *(const f32x4*)(Sc + p0);
      f32x4 vbo = *(const f32x4*)(So + p0);
      f32x4 vwc = *(const f32x4*)(Swc + p0);
      f32x4 acc[3][2];
#pragma unroll
      for (int m = 0; m < 2; ++m) {
        acc[0][m] = (f32x4){0.f, 0.f, 0.f, 0.f};
        acc[1][m] = (f32x4){0.f, 0.f, 0.f, 0.f};
        acc[2][m] = (f32x4){0.f, 0.f, 0.f, 0.f};
      }
#pragma unroll
      for (int sk = 0; sk < 2; ++sk)
#pragma unroll
        for (int m = 0; m < 2; ++m) {
          acc[0][m] = __builtin_amdgcn_mfma_f32_16x16x32_bf16(w[gg][0][sk], bx[m][sk], acc[0][m], 0, 0, 0);
          acc[1][m] = __builtin_amdgcn_mfma_f32_16x16x32_bf16(w[gg][1][sk], bx[m][sk], acc[1][m], 0, 0, 0);
          acc[2][m] = __builtin_amdgcn_mfma_f32_16x16x32_bf16(w[gg][2][sk], bx[m][sk], acc[2][m], 0, 0, 0);
        }
      // gates (prescaled, bias post-MFMA): ei=e^-zi, ec=e^2zc;
      // C=(ec-1)*rcp((1+ei)(1+ec)); eo=e^-(zo+wc*C); e2=e^2C;
      // H=(e2-1)*rcp((1+eo)(1+e2)).
#pragma unroll
      for (int m = 0; m < 2; ++m) {
        f32x4 z0 = acc[0][m] + vbi;
        f32x4 z1 = acc[1][m] + vbc;
        f32x4 ei, ec;
#pragma unroll
        for (int r = 0; r < 4; ++r) { ei[r] = fexp2(z0[r]); ec[r] = fexp2(z1[r]); }
        f32x4 den1 = (ei + 1.0f) * (ec + 1.0f);
        f32x4 rd1;
#pragma unroll
        for (int r = 0; r < 4; ++r) rd1[r] = frcp(den1[r]);
        f32x4 C = (ec - 1.0f) * rd1;
        f32x4 s2 = (acc[2][m] + vbo) + vwc * C;
        f32x4 t2 = C * TWOLOG2E;
        f32x4 eo, e2;
#pragma unroll
        for (int r = 0; r < 4; ++r) { eo[r] = fexp2(s2[r]); e2[r] = fexp2(t2[r]); }
        f32x4 den2 = (eo + 1.0f) * (e2 + 1.0f);
        f32x4 rd2;
#pragma unroll
        for (int r = 0; r < 4; ++r) rd2[r] = frcp(den2[r]);
        f32x4 H = (e2 - 1.0f) * rd2;
        hbuf[g][m][0] = cvt_pk_bf16(H[0], H[1]);
        hbuf[g][m][1] = cvt_pk_bf16(H[2], H[3]);
      }
    }
  }

  // ---- Phase 2: 2 halves x {8-load burst -> pin -> 2 s-blocks} ----
  f32x4 oacc[4][2];
#pragma unroll
  for (int t = 0; t < 4; ++t) {
    oacc[t][0] = (f32x4){0.f, 0.f, 0.f, 0.f};
    oacc[t][1] = (f32x4){0.f, 0.f, 0.f, 0.f};
  }
#pragma unroll
  for (int hf = 0; hf < 2; ++hf) {
    short8 af[2][4];                     // [ss][t] = 32 VGPR
#pragma unroll
    for (int ss = 0; ss < 2; ++ss)
#pragma unroll
      for (int t = 0; t < 4; ++t)
        af[ss][t] = *(const short8*)(ff + (t * 4 + (hf * 2 + ss)) * 512);
#pragma unroll
    for (int ss = 0; ss < 2; ++ss)
      asm volatile("" :: "v"(af[ss][0]), "v"(af[ss][1]), "v"(af[ss][2]), "v"(af[ss][3]));

#pragma unroll
    for (int ss = 0; ss < 2; ++ss) {
      const int s = hf * 2 + ss;
#pragma unroll
      for (int m = 0; m < 2; ++m) {
        U bu;
        bu.u[0] = hbuf[2 * s][m][0];
        bu.u[1] = hbuf[2 * s + 1][m][0];
        bu.u[2] = hbuf[2 * s][m][1];
        bu.u[3] = hbuf[2 * s + 1][m][1];
#pragma unroll
        for (int t = 0; t < 4; ++t)
          oacc[t][m] = __builtin_amdgcn_mfma_f32_16x16x32_bf16(af[ss][t], bu.s8, oacc[t][m], 0, 0, 0);
      }
    }
  }

  // ---- epilogue: add fc bias, coalesced float4 stores ----
#pragma unroll
  for (int t = 0; t < 4; ++t) {
    const int od0 = 16 * t + 4 * q;
    f32x4 fb = *(const f32x4*)(Fcb + od0);
#pragma unroll
    for (int m = 0; m < 2; ++m) {
      f32x4 v = oacc[t][m] + fb;
      *(f32x4*)(out + (row0 + 16 * m + c) * OUT_DIM + od0) = v;
    }
  }
}

extern "C" void kernel_launch(void* const* d_in, const int* in_sizes, int n_in,
                              void* d_out, int out_size, void* d_ws, size_t ws_size,
                              hipStream_t stream) {
  (void)in_sizes; (void)n_in; (void)out_size; (void)ws_size;
  const float* x    = (const float*)d_in[0];
  const float* W_i  = (const float*)d_in[3];
  const float* W_c  = (const float*)d_in[5];
  const float* W_o  = (const float*)d_in[6];
  const float* bg_i = (const float*)d_in[11];
  const float* bg_c = (const float*)d_in[13];
  const float* bg_o = (const float*)d_in[14];
  const float* wc_o = (const float*)d_in[17];
  const float* b_i  = (const float*)d_in[18];
  const float* b_c  = (const float*)d_in[20];
  const float* b_o  = (const float*)d_in[21];
  const float* fc_W = (const float*)d_in[22];
  const float* fc_b = (const float*)d_in[23];

  short* wfrag  = (short*)d_ws;
  short* fcfrag = (short*)((char*)d_ws + FCFRAG_OFF);
  float* bias   = (float*)((char*)d_ws + BIAS_OFF);

  repack_kernel<<<dim3(64), dim3(256), 0, stream>>>(
      W_i, W_c, W_o, fc_W, bg_i, bg_c, bg_o, b_i, b_c, b_o, wc_o, fc_b,
      wfrag, fcfrag, bias);

  const int nwg = N_ROWS / 32;              // 6250 single-wave WGs
  gclstm_fused<<<dim3(nwg), dim3(64), 0, stream>>>(
      x, wfrag, fcfrag, bias, (float*)d_out);
}